// Round 4
// baseline (675.604 us; speedup 1.0000x reference)
//
#include <hip/hip_runtime.h>

#define N_NODES 100000
#define N_EDGES 1200000
#define DIM     64
#define SCAN_B  256
#define NB      ((N_NODES + SCAN_B - 1) / SCAN_B)   // 391 scan blocks

typedef unsigned short ushort_t;

__device__ inline float bf2f(ushort_t u) {
    return __uint_as_float(((unsigned int)u) << 16);
}
__device__ inline ushort_t f2bf(float f) {
    unsigned int x = __float_as_uint(f);
    unsigned int r = x + 0x7fff + ((x >> 16) & 1);   // RNE
    return (ushort_t)(r >> 16);
}

// ---------------------------------------------------------------------------
// xW = x @ W.T + b  ->  bf16.  16 rows/block, x staged via float4, W^T padded.
__global__ __launch_bounds__(256) void linear_kernel(
        const float* __restrict__ x, const float* __restrict__ W,
        const float* __restrict__ b, ushort_t* __restrict__ xwb) {
    __shared__ float sWt[DIM * (DIM + 1)];
    __shared__ float sx[16][DIM];

    int t = threadIdx.x;
    int row0 = blockIdx.x * 16;

    for (int i = t; i < DIM * DIM; i += 256) {
        int d = i >> 6, k = i & 63;
        sWt[k * (DIM + 1) + d] = W[i];
    }
    {
        int lr = t >> 4, off = (t & 15) << 2;
        const float4 v = *(const float4*)(x + (size_t)(row0 + lr) * DIM + off);
        sx[lr][off + 0] = v.x; sx[lr][off + 1] = v.y;
        sx[lr][off + 2] = v.z; sx[lr][off + 3] = v.w;
    }
    __syncthreads();

    int d  = t & 63;
    int r0 = (t >> 6) * 4;

    float bd = b[d];
    float a0 = bd, a1 = bd, a2 = bd, a3 = bd;
    const float2* x0 = (const float2*)sx[r0 + 0];
    const float2* x1 = (const float2*)sx[r0 + 1];
    const float2* x2 = (const float2*)sx[r0 + 2];
    const float2* x3 = (const float2*)sx[r0 + 3];
    #pragma unroll
    for (int k2 = 0; k2 < DIM / 2; k2++) {
        float w0 = sWt[(2 * k2 + 0) * (DIM + 1) + d];
        float w1 = sWt[(2 * k2 + 1) * (DIM + 1) + d];
        float2 v0 = x0[k2], v1 = x1[k2], v2 = x2[k2], v3 = x3[k2];
        a0 = fmaf(v0.x, w0, a0); a0 = fmaf(v0.y, w1, a0);
        a1 = fmaf(v1.x, w0, a1); a1 = fmaf(v1.y, w1, a1);
        a2 = fmaf(v2.x, w0, a2); a2 = fmaf(v2.y, w1, a2);
        a3 = fmaf(v3.x, w0, a3); a3 = fmaf(v3.y, w1, a3);
    }
    size_t base = (size_t)(row0 + r0) * DIM + d;
    xwb[base + 0 * DIM] = f2bf(a0);
    xwb[base + 1 * DIM] = f2bf(a1);
    xwb[base + 2 * DIM] = f2bf(a2);
    xwb[base + 3 * DIM] = f2bf(a3);
}

// ---------------------------------------------------------------------------
__global__ void count_kernel(const int* __restrict__ row, const int* __restrict__ col,
                             int* __restrict__ cnt_r, int* __restrict__ cnt_c) {
    int i = blockIdx.x * blockDim.x + threadIdx.x;
    if (i * 4 >= N_EDGES) return;
    int4 r4 = ((const int4*)row)[i];
    int4 c4 = ((const int4*)col)[i];
    atomicAdd(&cnt_r[r4.x], 1); atomicAdd(&cnt_r[r4.y], 1);
    atomicAdd(&cnt_r[r4.z], 1); atomicAdd(&cnt_r[r4.w], 1);
    atomicAdd(&cnt_c[c4.x], 1); atomicAdd(&cnt_c[c4.y], 1);
    atomicAdd(&cnt_c[c4.z], 1); atomicAdd(&cnt_c[c4.w], 1);
}

// ---------------------------------------------------------------------------
// scan phase A (+ fused dinv computation)
__global__ void scan_a(const int* __restrict__ cnt_r, const int* __restrict__ cnt_c,
                       int* __restrict__ offsets, int* __restrict__ partials,
                       float* __restrict__ dinv_i, float* __restrict__ dinv_j) {
    __shared__ int s[SCAN_B];
    int t = threadIdx.x;
    int i = blockIdx.x * SCAN_B + t;
    int v = (i < N_NODES) ? cnt_r[i] : 0;
    if (i < N_NODES) {
        dinv_i[i] = rsqrtf(1.0f + (float)v);
        dinv_j[i] = rsqrtf(1.0f + (float)cnt_c[i]);
    }
    s[t] = v;
    __syncthreads();
    for (int off = 1; off < SCAN_B; off <<= 1) {
        int add = (t >= off) ? s[t - off] : 0;
        __syncthreads();
        s[t] += add;
        __syncthreads();
    }
    if (i < N_NODES) offsets[i] = s[t] - v;           // exclusive within block
    if (t == SCAN_B - 1) partials[blockIdx.x] = s[t]; // block total
}

// scan phase C with fused cross-block reduction (replaces old scan_b+scan_c):
// each block reduces partials[j<bid] itself (391 ints, L2-resident).
__global__ void scan_c(int* __restrict__ offsets, const int* __restrict__ partials,
                       int* __restrict__ cursor) {
    __shared__ int sred[SCAN_B];
    int t = threadIdx.x, bid = blockIdx.x;
    int v = 0;
    for (int j = t; j < NB; j += SCAN_B)
        if (j < bid) v += partials[j];
    sred[t] = v;
    __syncthreads();
    for (int off = SCAN_B / 2; off > 0; off >>= 1) {
        if (t < off) sred[t] += sred[t + off];
        __syncthreads();
    }
    int base = sred[0];
    int i = bid * SCAN_B + t;
    if (i < N_NODES) {
        int o = offsets[i] + base;
        offsets[i] = o;
        cursor[i]  = o;
    }
}

// ---------------------------------------------------------------------------
// bin edges by dst -> rec[pos] = {e, c}   (8 B/edge scattered, nothing else)
__global__ void bin_kernel(const int* __restrict__ row, const int* __restrict__ col,
                           int* __restrict__ cursor, int2* __restrict__ rec) {
    int e = blockIdx.x * blockDim.x + threadIdx.x;
    if (e >= N_EDGES) return;
    int r = row[e], c = col[e];
    int pos = atomicAdd(&cursor[r], 1);
    rec[pos] = make_int2(e, c);
}

// ---------------------------------------------------------------------------
// Gather v3: wave/node, 4 groups x 16 lanes, float4/lane. Depth-1 software
// pipeline on the full record (rec+ea+xw+vj). val recomputed from dinv.
__global__ __launch_bounds__(256) void gather_kernel(
        const int* __restrict__ offsets, const int* __restrict__ cnt_r,
        const int2* __restrict__ rec,
        const float* __restrict__ edge_attr, const ushort_t* __restrict__ xwb,
        const float* __restrict__ dinv_i, const float* __restrict__ dinv_j,
        const float* __restrict__ root, float* __restrict__ out) {
    int lane = threadIdx.x & 63;
    int g    = lane >> 4;
    int q    = (lane & 15) << 2;
    int n    = blockIdx.x * 4 + (threadIdx.x >> 6);

    int   start = offsets[n];
    int   cnt   = cnt_r[n];
    float di    = dinv_i[n];

    float4 acc = make_float4(0.f, 0.f, 0.f, 0.f);
    int k = g;
    if (k < cnt) {
        int2    rc = rec[start + k];
        float4  ea = *(const float4*)(edge_attr + (size_t)rc.x * DIM + q);
        ushort4 xu = *(const ushort4*)(xwb + (size_t)rc.y * DIM + q);
        float   vj = dinv_j[rc.y];
        for (;;) {
            int  kn   = k + 4;
            bool more = kn < cnt;
            int2 rcn; float4 ean; ushort4 xun; float vjn;
            if (more) {
                rcn = rec[start + kn];
                ean = *(const float4*)(edge_attr + (size_t)rcn.x * DIM + q);
                xun = *(const ushort4*)(xwb + (size_t)rcn.y * DIM + q);
                vjn = dinv_j[rcn.y];
            }
            float vv = di * vj;
            acc.x = fmaf(vv, ea.x + bf2f(xu.x), acc.x);
            acc.y = fmaf(vv, ea.y + bf2f(xu.y), acc.y);
            acc.z = fmaf(vv, ea.z + bf2f(xu.z), acc.z);
            acc.w = fmaf(vv, ea.w + bf2f(xu.w), acc.w);
            if (!more) break;
            k = kn; ea = ean; xu = xun; vj = vjn;
        }
    }

    acc.x += __shfl_xor(acc.x, 16); acc.y += __shfl_xor(acc.y, 16);
    acc.z += __shfl_xor(acc.z, 16); acc.w += __shfl_xor(acc.w, 16);
    acc.x += __shfl_xor(acc.x, 32); acc.y += __shfl_xor(acc.y, 32);
    acc.z += __shfl_xor(acc.z, 32); acc.w += __shfl_xor(acc.w, 32);

    if (g == 0) {
        float s = di * dinv_j[n];
        const ushort4 xu = *(const ushort4*)(xwb + (size_t)n * DIM + q);
        const float4  rt = *(const float4*)(root + q);
        float4 o;
        o.x = fmaxf(acc.x, 0.f) + fmaxf(bf2f(xu.x) + rt.x, 0.f) * s;
        o.y = fmaxf(acc.y, 0.f) + fmaxf(bf2f(xu.y) + rt.y, 0.f) * s;
        o.z = fmaxf(acc.z, 0.f) + fmaxf(bf2f(xu.z) + rt.z, 0.f) * s;
        o.w = fmaxf(acc.w, 0.f) + fmaxf(bf2f(xu.w) + rt.w, 0.f) * s;
        *(float4*)(out + (size_t)n * DIM + q) = o;
    }
}

// ---------------------------------------------------------------------------
extern "C" void kernel_launch(void* const* d_in, const int* in_sizes, int n_in,
                              void* d_out, int out_size, void* d_ws, size_t ws_size,
                              hipStream_t stream) {
    const float* x         = (const float*)d_in[0];
    const int*   edge_idx  = (const int*)d_in[1];
    const float* edge_attr = (const float*)d_in[2];
    const float* W         = (const float*)d_in[3];
    const float* b         = (const float*)d_in[4];
    const float* root_emb  = (const float*)d_in[5];
    float*       out       = (float*)d_out;

    const int* row = edge_idx;
    const int* col = edge_idx + N_EDGES;

    // ws: xwb[N*D] bf16 | cnt_r,cnt_c,dinv_i,dinv_j,offsets,cursor [N] |
    //     partials[1024] | rec[E] int2     (~24.8 MB)
    char* ws = (char*)d_ws;
    ushort_t* xwb      = (ushort_t*)ws;   ws += (size_t)N_NODES * DIM * 2;
    int*      cnt_r    = (int*)ws;        ws += (size_t)N_NODES * 4;
    int*      cnt_c    = (int*)ws;        ws += (size_t)N_NODES * 4;
    float*    dinv_i   = (float*)ws;      ws += (size_t)N_NODES * 4;
    float*    dinv_j   = (float*)ws;      ws += (size_t)N_NODES * 4;
    int*      offsets  = (int*)ws;        ws += (size_t)N_NODES * 4;
    int*      cursor   = (int*)ws;        ws += (size_t)N_NODES * 4;
    int*      partials = (int*)ws;        ws += 1024 * 4;
    int2*     rec      = (int2*)ws;       ws += (size_t)N_EDGES * 8;

    hipMemsetAsync(cnt_r, 0, (size_t)N_NODES * 2 * sizeof(int), stream);

    linear_kernel<<<N_NODES / 16, 256, 0, stream>>>(x, W, b, xwb);

    count_kernel<<<(N_EDGES / 4 + 255) / 256, 256, 0, stream>>>(row, col, cnt_r, cnt_c);

    scan_a<<<NB, SCAN_B, 0, stream>>>(cnt_r, cnt_c, offsets, partials, dinv_i, dinv_j);
    scan_c<<<NB, SCAN_B, 0, stream>>>(offsets, partials, cursor);

    bin_kernel<<<(N_EDGES + 255) / 256, 256, 0, stream>>>(row, col, cursor, rec);

    gather_kernel<<<N_NODES / 4, 256, 0, stream>>>(
        offsets, cnt_r, rec, edge_attr, xwb, dinv_i, dinv_j, root_emb, out);
}

// Round 5
// 599.533 us; speedup vs baseline: 1.1269x; 1.1269x over previous
//
#include <hip/hip_runtime.h>

#define N_NODES 100000
#define N_EDGES 1200000
#define DIM     64
#define SCAN_B  256
#define NB      ((N_NODES + SCAN_B - 1) / SCAN_B)      // 391 scan blocks
#define LIN_BLOCKS (N_NODES / 16)                      // 6250
#define CNT_BLOCKS ((N_EDGES / 4 + 255) / 256)         // 1172

typedef unsigned short ushort_t;

__device__ inline float bf2f(ushort_t u) {
    return __uint_as_float(((unsigned int)u) << 16);
}
__device__ inline ushort_t f2bf(float f) {
    unsigned int x = __float_as_uint(f);
    unsigned int r = x + 0x7fff + ((x >> 16) & 1);   // RNE
    return (ushort_t)(r >> 16);
}

// ---------------------------------------------------------------------------
// Fused: blocks [0,LIN_BLOCKS) do xW=x@W.T+b -> bf16;
//        blocks [LIN_BLOCKS, ...) do degree counts + per-edge rank.
// Independent work overlaps GEMM FMAs with count atomics.
__global__ __launch_bounds__(256) void prep_kernel(
        const float* __restrict__ x, const float* __restrict__ W,
        const float* __restrict__ b, ushort_t* __restrict__ xwb,
        const int* __restrict__ row, const int* __restrict__ col,
        int* __restrict__ cnt_r, int* __restrict__ cnt_c,
        int* __restrict__ rank) {
    __shared__ float sWt[DIM * (DIM + 1)];
    __shared__ float sx[16][DIM];

    int t = threadIdx.x;

    if (blockIdx.x >= LIN_BLOCKS) {
        // ---- count path: 4 edges/thread; rank = pre-increment row count ----
        int i = (blockIdx.x - LIN_BLOCKS) * 256 + t;
        if (i * 4 >= N_EDGES) return;
        int4 r4 = ((const int4*)row)[i];
        int4 c4 = ((const int4*)col)[i];
        int4 rk;
        rk.x = atomicAdd(&cnt_r[r4.x], 1);
        rk.y = atomicAdd(&cnt_r[r4.y], 1);
        rk.z = atomicAdd(&cnt_r[r4.z], 1);
        rk.w = atomicAdd(&cnt_r[r4.w], 1);
        ((int4*)rank)[i] = rk;
        atomicAdd(&cnt_c[c4.x], 1);
        atomicAdd(&cnt_c[c4.y], 1);
        atomicAdd(&cnt_c[c4.z], 1);
        atomicAdd(&cnt_c[c4.w], 1);
        return;
    }

    // ---- linear path ----
    int row0 = blockIdx.x * 16;
    for (int i = t; i < DIM * DIM; i += 256) {
        int d = i >> 6, k = i & 63;
        sWt[k * (DIM + 1) + d] = W[i];
    }
    {
        int lr = t >> 4, off = (t & 15) << 2;
        const float4 v = *(const float4*)(x + (size_t)(row0 + lr) * DIM + off);
        sx[lr][off + 0] = v.x; sx[lr][off + 1] = v.y;
        sx[lr][off + 2] = v.z; sx[lr][off + 3] = v.w;
    }
    __syncthreads();

    int d  = t & 63;
    int r0 = (t >> 6) * 4;

    float bd = b[d];
    float a0 = bd, a1 = bd, a2 = bd, a3 = bd;
    const float2* x0 = (const float2*)sx[r0 + 0];
    const float2* x1 = (const float2*)sx[r0 + 1];
    const float2* x2 = (const float2*)sx[r0 + 2];
    const float2* x3 = (const float2*)sx[r0 + 3];
    #pragma unroll
    for (int k2 = 0; k2 < DIM / 2; k2++) {
        float w0 = sWt[(2 * k2 + 0) * (DIM + 1) + d];
        float w1 = sWt[(2 * k2 + 1) * (DIM + 1) + d];
        float2 v0 = x0[k2], v1 = x1[k2], v2 = x2[k2], v3 = x3[k2];
        a0 = fmaf(v0.x, w0, a0); a0 = fmaf(v0.y, w1, a0);
        a1 = fmaf(v1.x, w0, a1); a1 = fmaf(v1.y, w1, a1);
        a2 = fmaf(v2.x, w0, a2); a2 = fmaf(v2.y, w1, a2);
        a3 = fmaf(v3.x, w0, a3); a3 = fmaf(v3.y, w1, a3);
    }
    size_t base = (size_t)(row0 + r0) * DIM + d;
    xwb[base + 0 * DIM] = f2bf(a0);
    xwb[base + 1 * DIM] = f2bf(a1);
    xwb[base + 2 * DIM] = f2bf(a2);
    xwb[base + 3 * DIM] = f2bf(a3);
}

// ---------------------------------------------------------------------------
// scan phase A (+ fused dinv computation)
__global__ void scan_a(const int* __restrict__ cnt_r, const int* __restrict__ cnt_c,
                       int* __restrict__ offsets, int* __restrict__ partials,
                       float* __restrict__ dinv_i, float* __restrict__ dinv_j) {
    __shared__ int s[SCAN_B];
    int t = threadIdx.x;
    int i = blockIdx.x * SCAN_B + t;
    int v = (i < N_NODES) ? cnt_r[i] : 0;
    if (i < N_NODES) {
        dinv_i[i] = rsqrtf(1.0f + (float)v);
        dinv_j[i] = rsqrtf(1.0f + (float)cnt_c[i]);
    }
    s[t] = v;
    __syncthreads();
    for (int off = 1; off < SCAN_B; off <<= 1) {
        int add = (t >= off) ? s[t - off] : 0;
        __syncthreads();
        s[t] += add;
        __syncthreads();
    }
    if (i < N_NODES) offsets[i] = s[t] - v;           // exclusive within block
    if (t == SCAN_B - 1) partials[blockIdx.x] = s[t]; // block total
}

// scan phase C with fused cross-block reduction
__global__ void scan_c(int* __restrict__ offsets, const int* __restrict__ partials) {
    __shared__ int sred[SCAN_B];
    int t = threadIdx.x, bid = blockIdx.x;
    int v = 0;
    for (int j = t; j < NB; j += SCAN_B)
        if (j < bid) v += partials[j];
    sred[t] = v;
    __syncthreads();
    for (int off = SCAN_B / 2; off > 0; off >>= 1) {
        if (t < off) sred[t] += sred[t + off];
        __syncthreads();
    }
    int base = sred[0];
    int i = bid * SCAN_B + t;
    if (i < N_NODES) offsets[i] += base;
}

// ---------------------------------------------------------------------------
// bin v3: NO atomics — pos = offsets[row] + rank. 4 edges/thread.
__global__ void bin_kernel(const int* __restrict__ row, const int* __restrict__ col,
                           const int* __restrict__ rank, const int* __restrict__ offsets,
                           int2* __restrict__ rec) {
    int i = blockIdx.x * blockDim.x + threadIdx.x;
    if (i * 4 >= N_EDGES) return;
    int4 r4 = ((const int4*)row)[i];
    int4 c4 = ((const int4*)col)[i];
    int4 k4 = ((const int4*)rank)[i];
    int e = i * 4;
    rec[offsets[r4.x] + k4.x] = make_int2(e + 0, c4.x);
    rec[offsets[r4.y] + k4.y] = make_int2(e + 1, c4.y);
    rec[offsets[r4.z] + k4.z] = make_int2(e + 2, c4.z);
    rec[offsets[r4.w] + k4.w] = make_int2(e + 3, c4.w);
}

// ---------------------------------------------------------------------------
// Gather v4: wave/node, 4 groups x 16 lanes, float4/lane. Depth-2 rec
// prefetch (sequential, unconditional over-read stays inside ws slack),
// depth-1 ea/xw/vj prefetch, epilogue loads issued before the loop.
__global__ __launch_bounds__(256) void gather_kernel(
        const int* __restrict__ offsets, const int* __restrict__ cnt_r,
        const int2* __restrict__ rec,
        const float* __restrict__ edge_attr, const ushort_t* __restrict__ xwb,
        const float* __restrict__ dinv_i, const float* __restrict__ dinv_j,
        const float* __restrict__ root, float* __restrict__ out) {
    int lane = threadIdx.x & 63;
    int g    = lane >> 4;
    int q    = (lane & 15) << 2;
    int n    = blockIdx.x * 4 + (threadIdx.x >> 6);

    int   start = offsets[n];
    int   cnt   = cnt_r[n];
    float di    = dinv_i[n];

    // epilogue data, issued early (L2/LLC resident)
    const ushort4 xun0 = *(const ushort4*)(xwb + (size_t)n * DIM + q);
    const float4  rt   = *(const float4*)(root + q);
    const float   vj0  = dinv_j[n];

    float4 acc = make_float4(0.f, 0.f, 0.f, 0.f);
    int k = g;
    if (k < cnt) {
        int2 rcB = rec[start + k];          // current record (in-bounds)
        int2 rcC = rec[start + k + 4];      // next record (over-read ok: ws slack)
        float4  ea = *(const float4*)(edge_attr + (size_t)rcB.x * DIM + q);
        ushort4 xu = *(const ushort4*)(xwb + (size_t)rcB.y * DIM + q);
        float   vj = dinv_j[rcB.y];
        for (;;) {
            int  kn   = k + 4;
            bool more = kn < cnt;
            int2 rcD  = rec[start + k + 8]; // rec 2 ahead, unconditional
            float4 ean; ushort4 xun; float vjn;
            if (more) {                     // rcC valid iff more
                ean = *(const float4*)(edge_attr + (size_t)rcC.x * DIM + q);
                xun = *(const ushort4*)(xwb + (size_t)rcC.y * DIM + q);
                vjn = dinv_j[rcC.y];
            }
            float vv = di * vj;
            acc.x = fmaf(vv, ea.x + bf2f(xu.x), acc.x);
            acc.y = fmaf(vv, ea.y + bf2f(xu.y), acc.y);
            acc.z = fmaf(vv, ea.z + bf2f(xu.z), acc.z);
            acc.w = fmaf(vv, ea.w + bf2f(xu.w), acc.w);
            if (!more) break;
            k = kn; ea = ean; xu = xun; vj = vjn; rcC = rcD;
        }
    }

    acc.x += __shfl_xor(acc.x, 16); acc.y += __shfl_xor(acc.y, 16);
    acc.z += __shfl_xor(acc.z, 16); acc.w += __shfl_xor(acc.w, 16);
    acc.x += __shfl_xor(acc.x, 32); acc.y += __shfl_xor(acc.y, 32);
    acc.z += __shfl_xor(acc.z, 32); acc.w += __shfl_xor(acc.w, 32);

    if (g == 0) {
        float s = di * vj0;
        float4 o;
        o.x = fmaxf(acc.x, 0.f) + fmaxf(bf2f(xun0.x) + rt.x, 0.f) * s;
        o.y = fmaxf(acc.y, 0.f) + fmaxf(bf2f(xun0.y) + rt.y, 0.f) * s;
        o.z = fmaxf(acc.z, 0.f) + fmaxf(bf2f(xun0.z) + rt.z, 0.f) * s;
        o.w = fmaxf(acc.w, 0.f) + fmaxf(bf2f(xun0.w) + rt.w, 0.f) * s;
        *(float4*)(out + (size_t)n * DIM + q) = o;
    }
}

// ---------------------------------------------------------------------------
extern "C" void kernel_launch(void* const* d_in, const int* in_sizes, int n_in,
                              void* d_out, int out_size, void* d_ws, size_t ws_size,
                              hipStream_t stream) {
    const float* x         = (const float*)d_in[0];
    const int*   edge_idx  = (const int*)d_in[1];
    const float* edge_attr = (const float*)d_in[2];
    const float* W         = (const float*)d_in[3];
    const float* b         = (const float*)d_in[4];
    const float* root_emb  = (const float*)d_in[5];
    float*       out       = (float*)d_out;

    const int* row = edge_idx;
    const int* col = edge_idx + N_EDGES;

    // ws: xwb[N*D] bf16 | cnt_r,cnt_c,dinv_i,dinv_j,offsets [N] | partials[1024]
    //     | rank[E] | rec[E] int2 (LAST: gather over-reads rec by <=64 B into
    //     the remaining ~1.17 GB of ws slack)                     (~29.6 MB)
    char* ws = (char*)d_ws;
    ushort_t* xwb      = (ushort_t*)ws;   ws += (size_t)N_NODES * DIM * 2;
    int*      cnt_r    = (int*)ws;        ws += (size_t)N_NODES * 4;
    int*      cnt_c    = (int*)ws;        ws += (size_t)N_NODES * 4;
    float*    dinv_i   = (float*)ws;      ws += (size_t)N_NODES * 4;
    float*    dinv_j   = (float*)ws;      ws += (size_t)N_NODES * 4;
    int*      offsets  = (int*)ws;        ws += (size_t)N_NODES * 4;
    int*      partials = (int*)ws;        ws += 1024 * 4;
    int*      rank     = (int*)ws;        ws += (size_t)N_EDGES * 4;
    int2*     rec      = (int2*)ws;       ws += (size_t)N_EDGES * 8;

    hipMemsetAsync(cnt_r, 0, (size_t)N_NODES * 2 * sizeof(int), stream);

    prep_kernel<<<LIN_BLOCKS + CNT_BLOCKS, 256, 0, stream>>>(
        x, W, b, xwb, row, col, cnt_r, cnt_c, rank);

    scan_a<<<NB, SCAN_B, 0, stream>>>(cnt_r, cnt_c, offsets, partials, dinv_i, dinv_j);
    scan_c<<<NB, SCAN_B, 0, stream>>>(offsets, partials);

    bin_kernel<<<CNT_BLOCKS, 256, 0, stream>>>(row, col, rank, offsets, rec);

    gather_kernel<<<N_NODES / 4, 256, 0, stream>>>(
        offsets, cnt_r, rec, edge_attr, xwb, dinv_i, dinv_j, root_emb, out);
}